// Round 1
// baseline (161.460 us; speedup 1.0000x reference)
//
#include <hip/hip_runtime.h>
#include <stdint.h>

#define DM_ 256
#define H_ 4
#define M_ 4096
#define KN_ 16
#define B_ 2
#define KPAD 68   // bf16 elems per LDS row: 136B row stride -> 2-lane/bank writes, clean b64 frag reads

typedef __attribute__((ext_vector_type(8))) short short8;
typedef __attribute__((ext_vector_type(4))) float f32x4;
typedef __attribute__((ext_vector_type(4))) unsigned short u16x4;

static __device__ __forceinline__ unsigned short f2bf(float x) {
  union { float f; uint32_t u; } v; v.f = x;
  uint32_t u = v.u + (0x7FFFu + ((v.u >> 16) & 1u));  // RNE
  return (unsigned short)(u >> 16);
}

// ---- weight prep: fp32 row-major (256x256) -> bf16 fragment-linear -------------------------
// layout: [kstep(8)][rowblk(16)][lane(64)][8 bf16] ; lane element: row=rowblk*16+(l&15),
// k=kstep*32+(l>>4)*8+j  == exactly the A-operand fragment of mfma_f32_16x16x32_bf16.
__global__ void prep_weights(const float* __restrict__ Wq, const float* __restrict__ Wk,
                             const float* __restrict__ Wv, const float* __restrict__ Wm,
                             unsigned short* __restrict__ Wswz) {
  int t = blockIdx.x * 256 + threadIdx.x;   // 32768 threads total
  int mat = t >> 13;
  int rem = t & 8191;
  int kstep = rem >> 10;
  int rowblk = (rem >> 6) & 15;
  int lane = rem & 63;
  const float* W = (mat == 0) ? Wq : (mat == 1) ? Wk : (mat == 2) ? Wv : Wm;
  int row = rowblk * 16 + (lane & 15);
  int k0 = kstep * 32 + (lane >> 4) * 8;
  unsigned short o[8];
#pragma unroll
  for (int j = 0; j < 8; ++j) o[j] = f2bf(W[row * DM_ + k0 + j]);
  unsigned short* dst = Wswz + (size_t)mat * 65536 + (size_t)(((kstep * 16 + rowblk) * 64 + lane) * 8);
  *(u16x4*)dst = *(u16x4*)o;
  *(u16x4*)(dst + 4) = *(u16x4*)(o + 4);
}

// ---- generic 1x1-conv projection: Out[b][co][m] = bias[co] + sum_c W[co][c] * X[b][c][m] ----
// grid = B * (M/32) = 256 blocks, 512 threads (8 waves: 4 row-waves x 2 col-waves)
__global__ __launch_bounds__(512, 2)
void proj_gemm(const float* __restrict__ X, const unsigned short* __restrict__ Wswz,
               const float* __restrict__ bias, float* __restrict__ Out) {
  __shared__ unsigned short Xlds[2][32][KPAD];
  const int tid = threadIdx.x;
  const int lane = tid & 63, wid = tid >> 6;
  const int wr = wid >> 1, wc = wid & 1;
  const int b = blockIdx.x >> 7;
  const int mt = blockIdx.x & 127;
  const int m0 = mt * 32;
  const float* Xb = X + (size_t)b * DM_ * M_;
  f32x4 acc[4] = {};
  const int scol = tid & 31;
  const int skb = (tid >> 5) * 4;
  float f[4];
#pragma unroll
  for (int i = 0; i < 4; ++i) f[i] = Xb[(size_t)(skb + i) * M_ + m0 + scol];
  for (int p = 0; p < 4; ++p) {
    const int cur = p & 1;
    {
      u16x4 u;
#pragma unroll
      for (int q = 0; q < 4; ++q) u[q] = f2bf(f[q]);
      *(u16x4*)&Xlds[cur][scol][skb] = u;
    }
    __syncthreads();
    if (p < 3) {
      const int cc = (p + 1) * 64;
#pragma unroll
      for (int i = 0; i < 4; ++i) f[i] = Xb[(size_t)(cc + skb + i) * M_ + m0 + scol];
    }
#pragma unroll
    for (int ks = 0; ks < 2; ++ks) {
      const int kgs = p * 2 + ks;
      short8 a[4];
#pragma unroll
      for (int fi = 0; fi < 4; ++fi)
        a[fi] = *(const short8*)(Wswz + (size_t)(((kgs * 16 + (wr * 4 + fi)) * 64 + lane) * 8));
      const int bcol = wc * 16 + (lane & 15);
      const int ko = ks * 32 + (lane >> 4) * 8;
      union { short8 s; u16x4 h[2]; } bu;
      bu.h[0] = *(const u16x4*)&Xlds[cur][bcol][ko];
      bu.h[1] = *(const u16x4*)&Xlds[cur][bcol][ko + 4];
#pragma unroll
      for (int fi = 0; fi < 4; ++fi)
        acc[fi] = __builtin_amdgcn_mfma_f32_16x16x32_bf16(a[fi], bu.s, acc[fi], 0, 0, 0);
    }
  }
  const int bcol = wc * 16 + (lane & 15);
#pragma unroll
  for (int fi = 0; fi < 4; ++fi) {
#pragma unroll
    for (int r = 0; r < 4; ++r) {
      const int co = wr * 64 + fi * 16 + (lane >> 4) * 4 + r;
      Out[(size_t)(b * DM_ + co) * M_ + m0 + bcol] = acc[fi][r] + bias[co];
    }
  }
}

// ---- fused K/V projection + attention ------------------------------------------------------
// grid = B * (M/8) = 1024 blocks, 512 threads. Per block: 8 m-positions -> 128 GEMM columns
// (col = mlocal*16 + kk). Phases 0..3: Kproj GEMM (chunked K=64), phase 3 tail: scores+softmax
// straight from acc fragments; phases 4..7: Vproj GEMM; tail: PV reduce + x write.
__global__ __launch_bounds__(512, 2)
void fused_attn(const float* __restrict__ key, const float* __restrict__ value,
                const float* __restrict__ qws,
                const unsigned short* __restrict__ Wk_swz, const unsigned short* __restrict__ Wv_swz,
                const float* __restrict__ bk, const float* __restrict__ bv,
                float* __restrict__ xws, float* __restrict__ psum) {
  __shared__ unsigned short Xlds[2][128][KPAD];   // 34816 B
  __shared__ float q_lds[8][DM_];                 // 8 KB  [mlocal][channel]
  __shared__ float bk_lds[DM_];                   // 1 KB
  __shared__ float sc_lds[4][4][8][16];           // 8 KB  [wrow][h][mlocal][kk]
  __shared__ float prob_lds[4][8][16];            // 2 KB
  __shared__ float x_lds[8][DM_];                 // 8 KB
  const int tid = threadIdx.x;
  const int lane = tid & 63, wid = tid >> 6;
  const int wr = wid >> 1, wc = wid & 1;
  const int b = blockIdx.x >> 9;
  const int mt = blockIdx.x & 511;
  const int m0 = mt * 8;
  const float* keyb = key + (size_t)b * DM_ * M_ * KN_;
  const float* valb = value + (size_t)b * DM_ * M_ * KN_;
  {
    const int c = tid >> 1, mh = (tid & 1) * 4;
    const float4 qv = *(const float4*)(qws + (size_t)(b * DM_ + c) * M_ + m0 + mh);
    q_lds[mh + 0][c] = qv.x; q_lds[mh + 1][c] = qv.y;
    q_lds[mh + 2][c] = qv.z; q_lds[mh + 3][c] = qv.w;
    if (tid < DM_) bk_lds[tid] = bk[tid];
  }
  f32x4 acc[4][4] = {};
  const int scol = tid & 127;              // staging column (m'*16+kk), contiguous in global
  const int skb = (tid >> 7) * 16;         // staging k-base within chunk
  const size_t colbase = (size_t)m0 * KN_ + scol;
  float f[16];
#pragma unroll
  for (int i = 0; i < 16; ++i) f[i] = keyb[(size_t)(skb + i) * (M_ * KN_) + colbase];
#pragma unroll 1
  for (int p = 0; p < 8; ++p) {
    const int cur = p & 1;
    // write staged chunk p (transposed [col][k], bf16)
#pragma unroll
    for (int j = 0; j < 4; ++j) {
      u16x4 u;
#pragma unroll
      for (int q = 0; q < 4; ++q) u[q] = f2bf(f[j * 4 + q]);
      *(u16x4*)&Xlds[cur][scol][skb + j * 4] = u;
    }
    __syncthreads();
    // issue loads for chunk p+1 (in flight during MFMA below)
    if (p < 7) {
      const float* src = (p < 3) ? keyb : valb;
      const int cc = ((p + 1) & 3) * 64;
#pragma unroll
      for (int i = 0; i < 16; ++i) f[i] = src[(size_t)(cc + skb + i) * (M_ * KN_) + colbase];
    }
    const unsigned short* Wsw = (p < 4) ? Wk_swz : Wv_swz;
#pragma unroll
    for (int ks = 0; ks < 2; ++ks) {
      const int kgs = (p & 3) * 2 + ks;
      short8 a[4];
#pragma unroll
      for (int fi = 0; fi < 4; ++fi)
        a[fi] = *(const short8*)(Wsw + (size_t)(((kgs * 16 + (wr * 4 + fi)) * 64 + lane) * 8));
      short8 bfr[4];
#pragma unroll
      for (int fj = 0; fj < 4; ++fj) {
        const int bcol = wc * 64 + fj * 16 + (lane & 15);
        const int ko = ks * 32 + (lane >> 4) * 8;
        union { short8 s; u16x4 h[2]; } bu;
        bu.h[0] = *(const u16x4*)&Xlds[cur][bcol][ko];
        bu.h[1] = *(const u16x4*)&Xlds[cur][bcol][ko + 4];
        bfr[fj] = bu.s;
      }
#pragma unroll
      for (int fi = 0; fi < 4; ++fi)
#pragma unroll
        for (int fj = 0; fj < 4; ++fj)
          acc[fi][fj] = __builtin_amdgcn_mfma_f32_16x16x32_bf16(a[fi], bfr[fj], acc[fi][fj], 0, 0, 0);
    }
    if (p == 3) {
      // ---- scores directly from acc fragments ----
      // acc[fi][fj][r]: channel c = wr*64+fi*16+(lane>>4)*4+r (so h=r, d=wr*16+fi*4+(lane>>4)),
      // column col = wc*64+fj*16+(lane&15) (so mlocal=wc*4+fj, kk=lane&15)
      float part[4][4];
#pragma unroll
      for (int h = 0; h < 4; ++h)
#pragma unroll
        for (int fj = 0; fj < 4; ++fj) part[h][fj] = 0.f;
#pragma unroll
      for (int fj = 0; fj < 4; ++fj) {
        const int mp = wc * 4 + fj;
#pragma unroll
        for (int fi = 0; fi < 4; ++fi) {
          const int d = wr * 16 + fi * 4 + (lane >> 4);
#pragma unroll
          for (int h = 0; h < 4; ++h) {
            const int c = 4 * d + h;
            part[h][fj] += q_lds[mp][c] * (acc[fi][fj][h] + bk_lds[c]);  // LDS broadcast reads
          }
        }
      }
#pragma unroll
      for (int h = 0; h < 4; ++h)
#pragma unroll
        for (int fj = 0; fj < 4; ++fj) {
          float v = part[h][fj];
          v += __shfl_xor(v, 16);
          v += __shfl_xor(v, 32);
          if (lane < 16) sc_lds[wr][h][wc * 4 + fj][lane] = v;
        }
      __syncthreads();
      {
        const int h = tid >> 7, mp = (tid >> 4) & 7, kk = tid & 15;
        float s = (sc_lds[0][h][mp][kk] + sc_lds[1][h][mp][kk] +
                   sc_lds[2][h][mp][kk] + sc_lds[3][h][mp][kk]) * 0.125f;  // * 1/sqrt(64)
        float mx = s;
#pragma unroll
        for (int d2 = 1; d2 < 16; d2 <<= 1) mx = fmaxf(mx, __shfl_xor(mx, d2));
        const float e = __expf(s - mx);
        float sm = e;
#pragma unroll
        for (int d2 = 1; d2 < 16; d2 <<= 1) sm += __shfl_xor(sm, d2);
        prob_lds[h][mp][kk] = e / sm;
      }
      __syncthreads();
      if (tid < 128) {
        const int mp = tid >> 4, kk = tid & 15;
        psum[(size_t)(b * M_ + m0 + mp) * KN_ + kk] =
            prob_lds[0][mp][kk] + prob_lds[1][mp][kk] + prob_lds[2][mp][kk] + prob_lds[3][mp][kk];
      }
      const f32x4 z = {0.f, 0.f, 0.f, 0.f};
#pragma unroll
      for (int fi = 0; fi < 4; ++fi)
#pragma unroll
        for (int fj = 0; fj < 4; ++fj) acc[fi][fj] = z;
    }
  }
  // ---- PV: x[c][mp] = sum_kk prob[h][mp][kk] * Vp   (kk = lane&15 -> 16-lane reduce) ----
#pragma unroll
  for (int fi = 0; fi < 4; ++fi)
#pragma unroll
    for (int fj = 0; fj < 4; ++fj) {
      const int mp = wc * 4 + fj;
#pragma unroll
      for (int r = 0; r < 4; ++r) {
        float v = prob_lds[r][mp][lane & 15] * acc[fi][fj][r];
        v += __shfl_xor(v, 1);
        v += __shfl_xor(v, 2);
        v += __shfl_xor(v, 4);
        v += __shfl_xor(v, 8);
        if ((lane & 15) == 0) x_lds[mp][wr * 64 + fi * 16 + (lane >> 4) * 4 + r] = v;
      }
    }
  __syncthreads();
  {
    const int c = tid >> 1, mh = (tid & 1) * 4;
    const float bvv = bv[c];  // sum(prob)=1 => v-bias adds directly
    float4 o;
    o.x = x_lds[mh + 0][c] + bvv;
    o.y = x_lds[mh + 1][c] + bvv;
    o.z = x_lds[mh + 2][c] + bvv;
    o.w = x_lds[mh + 3][c] + bvv;
    *(float4*)(xws + (size_t)(b * DM_ + c) * M_ + m0 + mh) = o;
  }
}

extern "C" void kernel_launch(void* const* d_in, const int* in_sizes, int n_in,
                              void* d_out, int out_size, void* d_ws, size_t ws_size,
                              hipStream_t stream) {
  const float* query = (const float*)d_in[0];
  const float* key   = (const float*)d_in[1];
  const float* value = (const float*)d_in[2];
  const float* Wq = (const float*)d_in[3];
  const float* bq = (const float*)d_in[4];
  const float* Wk = (const float*)d_in[5];
  const float* bk = (const float*)d_in[6];
  const float* Wv = (const float*)d_in[7];
  const float* bv = (const float*)d_in[8];
  const float* Wm = (const float*)d_in[9];
  const float* bm = (const float*)d_in[10];
  float* out  = (float*)d_out;
  float* psum = out + (size_t)B_ * DM_ * M_;   // outputs concatenated: out then prob_sum

  unsigned short* Wswz = (unsigned short*)d_ws;          // 4 * 65536 bf16 = 512 KB
  const size_t wbytes = (size_t)4 * 65536 * sizeof(unsigned short);
  const size_t qbytes = (size_t)B_ * DM_ * M_ * sizeof(float);  // 8 MB
  float* qws;
  if (ws_size >= wbytes + qbytes) {
    qws = (float*)((char*)d_ws + wbytes);
  } else {
    // fall back: stage q/x inside d_out[0..B*DM*M) — safe: every block reads its q tile before
    // writing its x tile for the same positions, and the final proj fully overwrites the region.
    qws = out;
  }
  float* xws = qws;  // alias q/x: per-block read-before-write ordering makes this safe

  prep_weights<<<dim3(128), dim3(256), 0, stream>>>(Wq, Wk, Wv, Wm, Wswz);
  proj_gemm<<<dim3(B_ * (M_ / 32)), dim3(512), 0, stream>>>(query, Wswz + 0 * 65536, bq, qws);
  fused_attn<<<dim3(B_ * (M_ / 8)), dim3(512), 0, stream>>>(key, value, qws,
                                                            Wswz + 1 * 65536, Wswz + 2 * 65536,
                                                            bk, bv, xws, psum);
  proj_gemm<<<dim3(B_ * (M_ / 32)), dim3(512), 0, stream>>>(xws, Wswz + 3 * 65536, bm, out);
}

// Round 2
// 131.821 us; speedup vs baseline: 1.2248x; 1.2248x over previous
//
#include <hip/hip_runtime.h>
#include <stdint.h>

#define DM_ 256
#define H_ 4
#define M_ 4096
#define KN_ 16
#define B_ 2
#define MK_ (M_*KN_)

typedef __attribute__((ext_vector_type(8))) short short8;
typedef __attribute__((ext_vector_type(4))) float f32x4;
typedef __attribute__((ext_vector_type(4))) unsigned short u16x4;

static __device__ __forceinline__ unsigned short f2bf(float x) {
  union { float f; uint32_t u; } v; v.f = x;
  uint32_t u = v.u + (0x7FFFu + ((v.u >> 16) & 1u));  // RNE
  return (unsigned short)(u >> 16);
}

// XOR swizzle for [col][k] bf16 tiles: f depends only on col, XORed into byte bits 4..6.
// Gives bank-floor b32/b64 transposed writes AND bank-floor ds_read_b128 fragment reads.
static __device__ __forceinline__ int swz128(int col, int kbyte) {   // row stride 128 B
  int f = ((col >> 2) & 7) ^ ((col & 1) << 2);
  return (col << 7) + (kbyte ^ (f << 4));
}
static __device__ __forceinline__ int swz512(int col, int kbyte) {   // row stride 512 B
  int f = ((col >> 2) & 7) ^ ((col & 1) << 2);
  return (col << 9) + (kbyte ^ (f << 4));
}

// ---- weight prep: fp32 row-major (256x256) -> bf16 fragment-linear (A-operand layout) ----
__global__ void prep_weights(const float* __restrict__ Wq, const float* __restrict__ Wk,
                             const float* __restrict__ Wv, const float* __restrict__ Wm,
                             unsigned short* __restrict__ Wswz) {
  int t = blockIdx.x * 256 + threadIdx.x;   // 32768 threads total
  int mat = t >> 13;
  int rem = t & 8191;
  int kstep = rem >> 10;
  int rowblk = (rem >> 6) & 15;
  int lane = rem & 63;
  const float* W = (mat == 0) ? Wq : (mat == 1) ? Wk : (mat == 2) ? Wv : Wm;
  int row = rowblk * 16 + (lane & 15);
  int k0 = kstep * 32 + (lane >> 4) * 8;
  unsigned short o[8];
#pragma unroll
  for (int j = 0; j < 8; ++j) o[j] = f2bf(W[row * DM_ + k0 + j]);
  unsigned short* dst = Wswz + (size_t)mat * 65536 + (size_t)(((kstep * 16 + rowblk) * 64 + lane) * 8);
  *(u16x4*)dst = *(u16x4*)o;
  *(u16x4*)(dst + 4) = *(u16x4*)(o + 4);
}

// ---- 1x1-conv projection: Out[b][co][m] = bias[co] + sum_c W[co][c] * X[b][c][m] ----------
// grid = B*(M/32) = 256 blocks, 512 threads. Single K=256 phase: stage whole K-panel
// (32 cols x 256 chans) via float4 loads into swizzled LDS, one sync, 8 kgs of MFMA with
// weight-fragment double buffering.
__global__ __launch_bounds__(512)
void proj_gemm(const float* __restrict__ X, const unsigned short* __restrict__ Wswz,
               const float* __restrict__ bias, float* __restrict__ Out) {
  __shared__ unsigned short Xl[32 * 256];   // 16 KB, swizzled [col][k]
  const int tid = threadIdx.x;
  const int lane = tid & 63, wid = tid >> 6;
  const int wr = wid >> 1, wc = wid & 1;
  const int b = blockIdx.x >> 7;
  const int m0 = (blockIdx.x & 127) * 32;
  const float* Xb = X + (size_t)b * DM_ * M_ + m0;
  // stage: 4 chans x 4 cols per thread (4 x float4)
  const int c4 = 4 * (tid & 7);
  const int ch0 = 4 * (tid >> 3);
  float4 f[4];
#pragma unroll
  for (int i = 0; i < 4; ++i) f[i] = *(const float4*)(Xb + (size_t)(ch0 + i) * M_ + c4);
#pragma unroll
  for (int j = 0; j < 4; ++j) {
    u16x4 u = { f2bf(((const float*)&f[0])[j]), f2bf(((const float*)&f[1])[j]),
                f2bf(((const float*)&f[2])[j]), f2bf(((const float*)&f[3])[j]) };
    *(u16x4*)((char*)Xl + swz512(c4 + j, 2 * ch0)) = u;
  }
  __syncthreads();
  f32x4 acc[4] = {};
  const int bcol = wc * 16 + (lane & 15);
  const int rdk = 16 * (lane >> 4);
  short8 a_cur[4], a_nxt[4];
#pragma unroll
  for (int fi = 0; fi < 4; ++fi)
    a_cur[fi] = *(const short8*)(Wswz + (size_t)(((wr * 4 + fi) * 64 + lane) * 8));
#pragma unroll
  for (int kgs = 0; kgs < 8; ++kgs) {
    if (kgs < 7) {
#pragma unroll
      for (int fi = 0; fi < 4; ++fi)
        a_nxt[fi] = *(const short8*)(Wswz + (size_t)(((((kgs + 1) * 16) + wr * 4 + fi) * 64 + lane) * 8));
    }
    short8 bb = *(const short8*)((const char*)Xl + swz512(bcol, 64 * kgs + rdk));
#pragma unroll
    for (int fi = 0; fi < 4; ++fi)
      acc[fi] = __builtin_amdgcn_mfma_f32_16x16x32_bf16(a_cur[fi], bb, acc[fi], 0, 0, 0);
#pragma unroll
    for (int fi = 0; fi < 4; ++fi) a_cur[fi] = a_nxt[fi];
  }
#pragma unroll
  for (int fi = 0; fi < 4; ++fi) {
#pragma unroll
    for (int r = 0; r < 4; ++r) {
      const int co = wr * 64 + fi * 16 + (lane >> 4) * 4 + r;
      Out[(size_t)(b * DM_ + co) * M_ + m0 + bcol] = acc[fi][r] + bias[co];
    }
  }
}

// ---- fused K/V projection + attention ------------------------------------------------------
// grid = B*(M/8) = 1024 blocks, 1024 threads (16 waves: 4 row x 4 col).
// Per block: 8 m-positions -> 128 GEMM cols (col = mlocal*16 + kk). Phases 0..3 Kproj,
// softmax from acc fragments at p==3, phases 4..7 Vproj, PV reduce at end.
// Per phase: write staged chunk -> sync -> A-frags FIRST, staging loads SECOND (in-order
// vmcnt keeps staging in flight across MFMA waits) -> b128 B-frags -> 16 MFMA.
__global__ __launch_bounds__(1024, 4)
void fused_attn(const float* __restrict__ key, const float* __restrict__ value,
                const float* __restrict__ qws,
                const unsigned short* __restrict__ Wk_swz, const unsigned short* __restrict__ Wv_swz,
                const float* __restrict__ bk, const float* __restrict__ bv,
                float* __restrict__ xws, float* __restrict__ psum) {
  __shared__ unsigned short Xlds[2][128 * 64];    // 32 KB, swizzled [col][k]
  __shared__ float q_lds[8][DM_];                 // 8 KB  [mlocal][channel]
  __shared__ float bk_lds[DM_];                   // 1 KB
  __shared__ float scx[4][4][8][16];              // 8 KB  scores [wr][h][mp][kk]; reused as x[8][256]
  __shared__ float prob_lds[4][8][16];            // 2 KB
  float (*x_lds)[DM_] = (float (*)[DM_])scx;
  const int tid = threadIdx.x;
  const int lane = tid & 63, wid = tid >> 6;      // wid 0..15
  const int wr = wid >> 2, wc = wid & 3;
  const int b = blockIdx.x >> 9;
  const int m0 = (blockIdx.x & 511) * 8;
  const float* keyb = key + (size_t)b * DM_ * MK_;
  const float* valb = value + (size_t)b * DM_ * MK_;
  {
    const int c = tid >> 2, mh = (tid & 3) * 2;
    const float2 qv = *(const float2*)(qws + (size_t)(b * DM_ + c) * M_ + m0 + mh);
    q_lds[mh][c] = qv.x; q_lds[mh + 1][c] = qv.y;
    if (tid < DM_) bk_lds[tid] = bk[tid];
  }
  f32x4 acc[4][2] = {};
  const int c4 = 4 * (tid & 31);                  // staging cols c4..c4+3
  const int ch = 2 * (tid >> 5);                  // staging chans ch, ch+1 (within chunk)
  const size_t colbase = (size_t)m0 * KN_ + c4;
  const int wkbyte = 4 * (tid >> 5);              // k-byte of chan pair in LDS row
  float4 fa, fb2;
  fa  = *(const float4*)(keyb + (size_t)ch * MK_ + colbase);
  fb2 = *(const float4*)(keyb + (size_t)(ch + 1) * MK_ + colbase);
  for (int p = 0; p < 8; ++p) {
    unsigned short* Xb = Xlds[p & 1];
    // write staged chunk p (transposed [col][k] bf16, swizzled, b32 per col)
#pragma unroll
    for (int j = 0; j < 4; ++j) {
      uint32_t u = (uint32_t)f2bf(((const float*)&fa)[j]) |
                   ((uint32_t)f2bf(((const float*)&fb2)[j]) << 16);
      *(uint32_t*)((char*)Xb + swz128(c4 + j, wkbyte)) = u;
    }
    __syncthreads();
    const unsigned short* Wsw = (p < 4) ? Wk_swz : Wv_swz;
    // A-fragments first: they are the only thing the MFMAs vmcnt-wait on, so the
    // staging loads issued below stay outstanding through the whole compute phase.
    short8 afr[2][4];
#pragma unroll
    for (int ks = 0; ks < 2; ++ks)
#pragma unroll
      for (int fi = 0; fi < 4; ++fi)
        afr[ks][fi] = *(const short8*)(Wsw +
            (size_t)(((((p & 3) * 2 + ks) * 16 + wr * 4 + fi) * 64 + lane) * 8));
    if (p < 7) {   // issue staging loads for chunk p+1
      const float* src = (p < 3) ? keyb : valb;
      const size_t base = (size_t)(((p + 1) & 3) * 64 + ch) * MK_ + colbase;
      fa  = *(const float4*)(src + base);
      fb2 = *(const float4*)(src + base + MK_);
    }
#pragma unroll
    for (int ks = 0; ks < 2; ++ks) {
      short8 bfr[2];
#pragma unroll
      for (int fj = 0; fj < 2; ++fj)
        bfr[fj] = *(const short8*)((const char*)Xb +
            swz128(wc * 32 + fj * 16 + (lane & 15), 64 * ks + 16 * (lane >> 4)));
#pragma unroll
      for (int fi = 0; fi < 4; ++fi)
#pragma unroll
        for (int fj = 0; fj < 2; ++fj)
          acc[fi][fj] = __builtin_amdgcn_mfma_f32_16x16x32_bf16(afr[ks][fi], bfr[fj], acc[fi][fj], 0, 0, 0);
    }
    if (p == 3) {
      // ---- scores straight from acc fragments ----
      // acc[fi][fj][r]: channel c = wr*64+fi*16+(lane>>4)*4+r  (d=c>>2, h=c&3=r)
      //                 col = wc*32+fj*16+(lane&15)  (mp = wc*2+fj, kk = lane&15)
      float part[4][2];
#pragma unroll
      for (int h = 0; h < 4; ++h)
#pragma unroll
        for (int fj = 0; fj < 2; ++fj) part[h][fj] = 0.f;
#pragma unroll
      for (int fj = 0; fj < 2; ++fj) {
        const int mp = wc * 2 + fj;
#pragma unroll
        for (int fi = 0; fi < 4; ++fi) {
          const int d = wr * 16 + fi * 4 + (lane >> 4);
#pragma unroll
          for (int h = 0; h < 4; ++h) {
            const int c = 4 * d + h;
            part[h][fj] += q_lds[mp][c] * (acc[fi][fj][h] + bk_lds[c]);
          }
        }
      }
#pragma unroll
      for (int h = 0; h < 4; ++h)
#pragma unroll
        for (int fj = 0; fj < 2; ++fj) {
          float v = part[h][fj];
          v += __shfl_xor(v, 16);
          v += __shfl_xor(v, 32);
          if (lane < 16) scx[wr][h][wc * 2 + fj][lane] = v;
        }
      __syncthreads();
      if (tid < 512) {
        const int h = tid >> 7, mp = (tid >> 4) & 7, kk = tid & 15;
        float s = (scx[0][h][mp][kk] + scx[1][h][mp][kk] +
                   scx[2][h][mp][kk] + scx[3][h][mp][kk]) * 0.125f;   // * 1/sqrt(64)
        float mx = s;
#pragma unroll
        for (int d2 = 1; d2 < 16; d2 <<= 1) mx = fmaxf(mx, __shfl_xor(mx, d2));
        const float e = __expf(s - mx);
        float sm = e;
#pragma unroll
        for (int d2 = 1; d2 < 16; d2 <<= 1) sm += __shfl_xor(sm, d2);
        prob_lds[h][mp][kk] = e / sm;
      }
      __syncthreads();
      if (tid < 128) {
        const int mp = tid >> 4, kk = tid & 15;
        psum[(size_t)(b * M_ + m0 + mp) * KN_ + kk] =
            prob_lds[0][mp][kk] + prob_lds[1][mp][kk] + prob_lds[2][mp][kk] + prob_lds[3][mp][kk];
      }
      const f32x4 z = {0.f, 0.f, 0.f, 0.f};
#pragma unroll
      for (int fi = 0; fi < 4; ++fi)
#pragma unroll
        for (int fj = 0; fj < 2; ++fj) acc[fi][fj] = z;
    }
  }
  // ---- PV: x[c][mp] = sum_kk prob[h][mp][kk] * Vp  (kk = lane&15 -> 16-lane reduce) ----
#pragma unroll
  for (int fi = 0; fi < 4; ++fi)
#pragma unroll
    for (int fj = 0; fj < 2; ++fj) {
      const int mp = wc * 2 + fj;
#pragma unroll
      for (int r = 0; r < 4; ++r) {
        float v = prob_lds[r][mp][lane & 15] * acc[fi][fj][r];
        v += __shfl_xor(v, 1);
        v += __shfl_xor(v, 2);
        v += __shfl_xor(v, 4);
        v += __shfl_xor(v, 8);
        if ((lane & 15) == 0) x_lds[mp][wr * 64 + fi * 16 + (lane >> 4) * 4 + r] = v;
      }
    }
  __syncthreads();
  {
    const int c = tid >> 2, mh = (tid & 3) * 2;
    const float bvv = bv[c];   // sum(prob)=1 => v-bias adds directly
    float2 o;
    o.x = x_lds[mh][c] + bvv;
    o.y = x_lds[mh + 1][c] + bvv;
    *(float2*)(xws + (size_t)(b * DM_ + c) * M_ + m0 + mh) = o;
  }
}

extern "C" void kernel_launch(void* const* d_in, const int* in_sizes, int n_in,
                              void* d_out, int out_size, void* d_ws, size_t ws_size,
                              hipStream_t stream) {
  const float* query = (const float*)d_in[0];
  const float* key   = (const float*)d_in[1];
  const float* value = (const float*)d_in[2];
  const float* Wq = (const float*)d_in[3];
  const float* bq = (const float*)d_in[4];
  const float* Wk = (const float*)d_in[5];
  const float* bk = (const float*)d_in[6];
  const float* Wv = (const float*)d_in[7];
  const float* bv = (const float*)d_in[8];
  const float* Wm = (const float*)d_in[9];
  const float* bm = (const float*)d_in[10];
  float* out  = (float*)d_out;
  float* psum = out + (size_t)B_ * DM_ * M_;   // outputs concatenated: out then prob_sum

  unsigned short* Wswz = (unsigned short*)d_ws;          // 4 * 65536 bf16 = 512 KB
  const size_t wbytes = (size_t)4 * 65536 * sizeof(unsigned short);
  const size_t qbytes = (size_t)B_ * DM_ * M_ * sizeof(float);  // 8 MB
  float* qws;
  if (ws_size >= wbytes + qbytes) {
    qws = (float*)((char*)d_ws + wbytes);
  } else {
    // fall back: stage q/x inside d_out[0..B*DM*M) — safe: per-block read-before-write
    // ordering, and the final proj fully overwrites the region.
    qws = out;
  }
  float* xws = qws;  // alias q/x: per-block read-before-write ordering makes this safe

  prep_weights<<<dim3(128), dim3(256), 0, stream>>>(Wq, Wk, Wv, Wm, Wswz);
  proj_gemm<<<dim3(B_ * (M_ / 32)), dim3(512), 0, stream>>>(query, Wswz + 0 * 65536, bq, qws);
  fused_attn<<<dim3(B_ * (M_ / 8)), dim3(1024), 0, stream>>>(key, value, qws,
                                                             Wswz + 1 * 65536, Wswz + 2 * 65536,
                                                             bk, bv, xws, psum);
  proj_gemm<<<dim3(B_ * (M_ / 32)), dim3(512), 0, stream>>>(xws, Wswz + 3 * 65536, bm, out);
}

// Round 3
// 131.504 us; speedup vs baseline: 1.2278x; 1.0024x over previous
//
#include <hip/hip_runtime.h>
#include <stdint.h>

#define DM_ 256
#define H_ 4
#define M_ 4096
#define KN_ 16
#define B_ 2
#define MK_ (M_*KN_)

typedef __attribute__((ext_vector_type(8))) short short8;
typedef __attribute__((ext_vector_type(4))) float f32x4;
typedef __attribute__((ext_vector_type(4))) unsigned short u16x4;

static __device__ __forceinline__ unsigned short f2bf(float x) {
  union { float f; uint32_t u; } v; v.f = x;
  uint32_t u = v.u + (0x7FFFu + ((v.u >> 16) & 1u));  // RNE
  return (unsigned short)(u >> 16);
}
static __device__ __forceinline__ float bf2f(unsigned short x) {
  union { uint32_t u; float f; } v; v.u = ((uint32_t)x) << 16; return v.f;
}

// XOR swizzle for [col][k] bf16 tiles (row stride 512 B), bank-floor b128 reads/writes.
static __device__ __forceinline__ int swz512(int col, int kbyte) {
  int f = ((col >> 2) & 7) ^ ((col & 1) << 2);
  return (col << 9) + (kbyte ^ (f << 4));
}
static __device__ __forceinline__ int swz128(int col, int kbyte) {
  int f = ((col >> 2) & 7) ^ ((col & 1) << 2);
  return (col << 7) + (kbyte ^ (f << 4));
}

// ==================== NEW PATH ==========================================================
// Algebraic refactor: scores = qW·key (qW = W2T×query), pv = prob-contracted value,
// out = Wmv×pv + btot.  Hot kernel is pure streaming (no MFMA, no staging barriers).

// ---- prep2: weight products, fragment-linear bf16, fused biases ------------------------
// W2T rows r=(h*256+c), k=c'  : W2T[r][c'] = sum_d Wq[4d+h][c']*Wk[4d+h][c]
// Wmv rows o, k=(c*4+h)       : Wmv[o][k]  = sum_d Wm[o][4d+h]*Wv[4d+h][c]
// qb2[r] = sum_d bq[4d+h]*Wk[4d+h][c] ;  btot[o] = bm[o] + sum_{dh} Wm[o][dh]*bv[dh]
// (q·bk score term is constant per (h,m) => softmax-invariant => dropped.)
__global__ void prep2(const float* __restrict__ Wq, const float* __restrict__ bq,
                      const float* __restrict__ Wk, const float* __restrict__ Wv,
                      const float* __restrict__ bv, const float* __restrict__ Wm,
                      const float* __restrict__ bm,
                      unsigned short* __restrict__ W2T, unsigned short* __restrict__ Wmv,
                      float* __restrict__ qb2, float* __restrict__ btot) {
  int t = blockIdx.x * 512 + threadIdx.x;
  if (t < 262144) {                       // W2T fragment-linear [kstep8][rowblk64][lane][8]
    int j = t & 7, lane = (t >> 3) & 63, rowblk = (t >> 9) & 63, kstep = t >> 15;
    int row = rowblk * 16 + (lane & 15);
    int k = kstep * 32 + (lane >> 4) * 8 + j;
    int h = row >> 8, c = row & 255;
    float v = 0.f;
    for (int d = 0; d < 64; ++d) v += Wq[(4 * d + h) * 256 + k] * Wk[(4 * d + h) * 256 + c];
    W2T[t] = f2bf(v);
  } else if (t < 524288) {                // Wmv fragment-linear [kstep32][rowblk16][lane][8]
    int e = t - 262144;
    int j = e & 7, lane = (e >> 3) & 63, rowblk = (e >> 9) & 15, kstep = e >> 13;
    int o = rowblk * 16 + (lane & 15);
    int kidx = kstep * 32 + (lane >> 4) * 8 + j;
    int c = kidx >> 2, h = kidx & 3;
    float v = 0.f;
    for (int d = 0; d < 64; ++d) v += Wm[o * 256 + 4 * d + h] * Wv[(4 * d + h) * 256 + c];
    Wmv[e] = f2bf(v);
  } else if (t < 525312) {
    int r = t - 524288; int h = r >> 8, c = r & 255;
    float v = 0.f;
    for (int d = 0; d < 64; ++d) v += bq[4 * d + h] * Wk[(4 * d + h) * 256 + c];
    qb2[r] = v;
  } else if (t < 525568) {
    int o = t - 525312;
    float v = bm[o];
    for (int c2 = 0; c2 < 256; ++c2) v += Wm[o * 256 + c2] * bv[c2];
    btot[o] = v;
  }
}

// ---- qw_gemm: qW[b][r][m] (bf16) = W2T × query + qb2 ; grid = B*4rt*128mt --------------
__global__ __launch_bounds__(512)
void qw_gemm(const float* __restrict__ query, const unsigned short* __restrict__ W2T,
             const float* __restrict__ qb2, unsigned short* __restrict__ qWbuf) {
  __shared__ unsigned short Xl[32 * 256];
  const int tid = threadIdx.x;
  const int lane = tid & 63, wid = tid >> 6;
  const int wr = wid >> 1, wc = wid & 1;
  const int mt = blockIdx.x & 127;
  const int rt = (blockIdx.x >> 7) & 3;
  const int b = blockIdx.x >> 9;
  const int m0 = mt * 32;
  const float* Xb = query + (size_t)b * DM_ * M_ + m0;
  const int c4 = 4 * (tid & 7);
  const int ch0 = 4 * (tid >> 3);
  float4 f[4];
#pragma unroll
  for (int i = 0; i < 4; ++i) f[i] = *(const float4*)(Xb + (size_t)(ch0 + i) * M_ + c4);
#pragma unroll
  for (int j = 0; j < 4; ++j) {
    u16x4 u = { f2bf(((const float*)&f[0])[j]), f2bf(((const float*)&f[1])[j]),
                f2bf(((const float*)&f[2])[j]), f2bf(((const float*)&f[3])[j]) };
    *(u16x4*)((char*)Xl + swz512(c4 + j, 2 * ch0)) = u;
  }
  __syncthreads();
  f32x4 acc[4] = {};
  const int bcol = wc * 16 + (lane & 15);
  const int rdk = 16 * (lane >> 4);
  short8 a_cur[4], a_nxt[4];
#pragma unroll
  for (int fi = 0; fi < 4; ++fi)
    a_cur[fi] = *(const short8*)(W2T + (size_t)(((0 * 64 + rt * 16 + wr * 4 + fi) * 64 + lane) * 8));
#pragma unroll
  for (int kgs = 0; kgs < 8; ++kgs) {
    if (kgs < 7) {
#pragma unroll
      for (int fi = 0; fi < 4; ++fi)
        a_nxt[fi] = *(const short8*)(W2T + (size_t)((((kgs + 1) * 64 + rt * 16 + wr * 4 + fi) * 64 + lane) * 8));
    }
    short8 bb = *(const short8*)((const char*)Xl + swz512(bcol, 64 * kgs + rdk));
#pragma unroll
    for (int fi = 0; fi < 4; ++fi)
      acc[fi] = __builtin_amdgcn_mfma_f32_16x16x32_bf16(a_cur[fi], bb, acc[fi], 0, 0, 0);
#pragma unroll
    for (int fi = 0; fi < 4; ++fi) a_cur[fi] = a_nxt[fi];
  }
#pragma unroll
  for (int fi = 0; fi < 4; ++fi) {
#pragma unroll
    for (int r = 0; r < 4; ++r) {
      const int rr = rt * 256 + wr * 64 + fi * 16 + (lane >> 4) * 4 + r;
      qWbuf[(size_t)(b * 1024 + rr) * M_ + m0 + bcol] = f2bf(acc[fi][r] + qb2[rr]);
    }
  }
}

// ---- attn_stream: scores + softmax + psum + pv, pure streaming -------------------------
// grid = B*(M/8) = 1024, 512 threads (8 waves). Wave w owns chans w*32..w*32+31.
// Lane: cols col0..col0+3 (col0=4*(lane&31)), chan-half = lane>>5.
__global__ __launch_bounds__(512)
void attn_stream(const float* __restrict__ key, const float* __restrict__ value,
                 const unsigned short* __restrict__ qWbuf,
                 unsigned short* __restrict__ pvbuf, float* __restrict__ psum) {
  __shared__ float shA[256 * 32];        // 32KB: qW [c][m][h] during key pass, pv [c][m][h] after
  __shared__ float scx[8][4][128];       // 16KB partial scores [wave][h][col]
  __shared__ float prob_lds[4][8][16];   // 2KB
  const int tid = threadIdx.x;
  const int lane = tid & 63, w = tid >> 6;
  const int b = blockIdx.x >> 9;
  const int mt = blockIdx.x & 511;
  const int m0 = mt * 8;
  // qW fill: 2 rows (h,c) per thread, 8 bf16 each -> shA[c][m][h]
#pragma unroll
  for (int p = 0; p < 2; ++p) {
    const int r = tid * 2 + p;
    const int h = r >> 8, c = r & 255;
    uint4 v = *(const uint4*)(qWbuf + (size_t)(b * 1024 + r) * M_ + m0);
    const uint32_t* vu = (const uint32_t*)&v;
#pragma unroll
    for (int m = 0; m < 8; ++m)
      shA[c * 32 + m * 4 + h] = bf2f((unsigned short)(vu[m >> 1] >> ((m & 1) * 16)));
  }
  const int cb = w * 32;
  const int chalf = lane >> 5;
  const int colb = m0 * KN_ + 4 * (lane & 31);
  const int mloc = (lane & 31) >> 2;
  const int kk0 = 4 * (lane & 3);
  const float* kp0 = key + (size_t)b * DM_ * MK_ + (size_t)(cb + chalf) * MK_ + colb;
  f32x4 f0 = *(const f32x4*)kp0;
  f32x4 f1 = *(const f32x4*)(kp0 + 2 * (size_t)MK_);
  __syncthreads();
  // ---- key pass: s[h][j] += qW[c][m][h] * key[c][col0+j] ----
  f32x4 s4[4] = {};
  const int qb0 = (cb + chalf) * 32 + mloc * 4;
#pragma unroll
  for (int i = 0; i < 16; i += 2) {
    {
      f32x4 qv = *(const f32x4*)&shA[qb0 + i * 64];
#pragma unroll
      for (int h = 0; h < 4; ++h) s4[h] += f0 * qv[h];
      if (i + 2 < 16) f0 = *(const f32x4*)(kp0 + (size_t)(2 * (i + 2)) * MK_);
    }
    {
      f32x4 qv = *(const f32x4*)&shA[qb0 + (i + 1) * 64];
#pragma unroll
      for (int h = 0; h < 4; ++h) s4[h] += f1 * qv[h];
      if (i + 3 < 16) f1 = *(const f32x4*)(kp0 + (size_t)(2 * (i + 3)) * MK_);
    }
  }
#pragma unroll
  for (int h = 0; h < 4; ++h)
#pragma unroll
    for (int j = 0; j < 4; ++j) {
      float v = s4[h][j];
      v += __shfl_xor(v, 32);
      s4[h][j] = v;
    }
  if (lane < 32) {
#pragma unroll
    for (int h = 0; h < 4; ++h) *(f32x4*)&scx[w][h][4 * lane] = s4[h];
  }
  // issue value prefetch before softmax section
  const float* vp0 = value + (size_t)b * DM_ * MK_ + (size_t)(cb + chalf) * MK_ + colb;
  f0 = *(const f32x4*)vp0;
  f1 = *(const f32x4*)(vp0 + 2 * (size_t)MK_);
  __syncthreads();
  // ---- score finish + softmax (tid = h2*128 + col) ----
  {
    const int h2 = tid >> 7, col = tid & 127;
    float sc = 0.f;
#pragma unroll
    for (int w2 = 0; w2 < 8; ++w2) sc += scx[w2][h2][col];
    sc *= 0.125f;                         // 1/sqrt(64)
    float mx = sc;
#pragma unroll
    for (int d2 = 1; d2 < 16; d2 <<= 1) mx = fmaxf(mx, __shfl_xor(mx, d2));
    const float e = __expf(sc - mx);
    float sm = e;
#pragma unroll
    for (int d2 = 1; d2 < 16; d2 <<= 1) sm += __shfl_xor(sm, d2);
    prob_lds[h2][col >> 4][col & 15] = e / sm;
  }
  __syncthreads();
  if (tid < 128) {
    const int m = tid >> 4, kk = tid & 15;
    psum[(size_t)(b * M_ + m0 + m) * KN_ + kk] =
        prob_lds[0][m][kk] + prob_lds[1][m][kk] + prob_lds[2][m][kk] + prob_lds[3][m][kk];
  }
  f32x4 pr[4];
#pragma unroll
  for (int h = 0; h < 4; ++h) pr[h] = *(const f32x4*)&prob_lds[h][mloc][kk0];
  // ---- value pass: pv[c][m][h] = sum_kk prob[h][m][kk]*value[c][col] (shA reused) ----
#pragma unroll
  for (int i = 0; i < 16; i += 2) {
#pragma unroll
    for (int half = 0; half < 2; ++half) {
      const f32x4 vv = half ? f1 : f0;
      float pp[4];
#pragma unroll
      for (int h = 0; h < 4; ++h)
        pp[h] = fmaf(pr[h][0], vv[0], fmaf(pr[h][1], vv[1], fmaf(pr[h][2], vv[2], pr[h][3] * vv[3])));
#pragma unroll
      for (int h = 0; h < 4; ++h) {
        pp[h] += __shfl_xor(pp[h], 1);
        pp[h] += __shfl_xor(pp[h], 2);
      }
      if ((lane & 3) == 0) {
        const int c = cb + 2 * (i + half) + chalf;
        f32x4 o = {pp[0], pp[1], pp[2], pp[3]};
        *(f32x4*)&shA[c * 32 + mloc * 4] = o;
      }
      if (half == 0) { if (i + 2 < 16) f0 = *(const f32x4*)(vp0 + (size_t)(2 * (i + 2)) * MK_); }
      else           { if (i + 3 < 16) f1 = *(const f32x4*)(vp0 + (size_t)(2 * (i + 3)) * MK_); }
    }
  }
  __syncthreads();
  // ---- pv writeout: pv[b][m][k=(c*4+h)] bf16, wave w handles m=w, 2KB contiguous rows ----
  {
    unsigned short o16[16];
#pragma unroll
    for (int ci = 0; ci < 4; ++ci) {
      f32x4 v = *(const f32x4*)&shA[(lane * 4 + ci) * 32 + w * 4];
#pragma unroll
      for (int h = 0; h < 4; ++h) o16[ci * 4 + h] = f2bf(v[h]);
    }
    unsigned short* dst = pvbuf + ((size_t)(b * M_ + m0 + w) * 1024 + lane * 16);
    *(uint4*)dst = *(const uint4*)&o16[0];
    *(uint4*)(dst + 8) = *(const uint4*)&o16[8];
  }
}

// ---- out_gemm: out[b][o][m] = Wmv × pv + btot ; grid = B*128, K=1024 in 4 phases -------
__global__ __launch_bounds__(512)
void out_gemm(const unsigned short* __restrict__ pvbuf, const unsigned short* __restrict__ Wmv,
              const float* __restrict__ btot, float* __restrict__ Out) {
  __shared__ unsigned short Xl[2][32 * 256];
  const int tid = threadIdx.x;
  const int lane = tid & 63, wid = tid >> 6;
  const int wr = wid >> 1, wc = wid & 1;
  const int b = blockIdx.x >> 7;
  const int m0 = (blockIdx.x & 127) * 32;
  const int scol = tid & 31, sq = tid >> 5;      // staging: col, k-16-group
  const int bcol = wc * 16 + (lane & 15);
  const int rdk = 16 * (lane >> 4);
  f32x4 acc[4] = {};
  for (int kp = 0; kp < 4; ++kp) {
    {
      const unsigned short* src = pvbuf + ((size_t)(b * M_ + m0 + scol) * 1024 + kp * 256 + sq * 16);
      uint4 v0 = *(const uint4*)src;
      uint4 v1 = *(const uint4*)(src + 8);
      *(uint4*)((char*)Xl[kp & 1] + swz512(scol, sq * 32)) = v0;
      *(uint4*)((char*)Xl[kp & 1] + swz512(scol, sq * 32 + 16)) = v1;
    }
    __syncthreads();
    short8 a_cur[4], a_nxt[4];
#pragma unroll
    for (int fi = 0; fi < 4; ++fi)
      a_cur[fi] = *(const short8*)(Wmv + (size_t)((((kp * 8) * 16 + wr * 4 + fi) * 64 + lane) * 8));
#pragma unroll
    for (int kgs = 0; kgs < 8; ++kgs) {
      if (kgs < 7) {
#pragma unroll
        for (int fi = 0; fi < 4; ++fi)
          a_nxt[fi] = *(const short8*)(Wmv + (size_t)((((kp * 8 + kgs + 1) * 16 + wr * 4 + fi) * 64 + lane) * 8));
      }
      short8 bb = *(const short8*)((const char*)Xl[kp & 1] + swz512(bcol, 64 * kgs + rdk));
#pragma unroll
      for (int fi = 0; fi < 4; ++fi)
        acc[fi] = __builtin_amdgcn_mfma_f32_16x16x32_bf16(a_cur[fi], bb, acc[fi], 0, 0, 0);
#pragma unroll
      for (int fi = 0; fi < 4; ++fi) a_cur[fi] = a_nxt[fi];
    }
    if (kp < 3) __syncthreads();
  }
#pragma unroll
  for (int fi = 0; fi < 4; ++fi) {
#pragma unroll
    for (int r = 0; r < 4; ++r) {
      const int o = wr * 64 + fi * 16 + (lane >> 4) * 4 + r;
      Out[(size_t)(b * DM_ + o) * M_ + m0 + bcol] = acc[fi][r] + btot[o];
    }
  }
}

// ==================== OLD PATH (fallback if workspace too small) ========================
__global__ void prep_weights(const float* __restrict__ Wq, const float* __restrict__ Wk,
                             const float* __restrict__ Wv, const float* __restrict__ Wm,
                             unsigned short* __restrict__ Wswz) {
  int t = blockIdx.x * 256 + threadIdx.x;
  int mat = t >> 13;
  int rem = t & 8191;
  int kstep = rem >> 10;
  int rowblk = (rem >> 6) & 15;
  int lane = rem & 63;
  const float* W = (mat == 0) ? Wq : (mat == 1) ? Wk : (mat == 2) ? Wv : Wm;
  int row = rowblk * 16 + (lane & 15);
  int k0 = kstep * 32 + (lane >> 4) * 8;
  unsigned short o[8];
#pragma unroll
  for (int j = 0; j < 8; ++j) o[j] = f2bf(W[row * DM_ + k0 + j]);
  unsigned short* dst = Wswz + (size_t)mat * 65536 + (size_t)(((kstep * 16 + rowblk) * 64 + lane) * 8);
  *(u16x4*)dst = *(u16x4*)o;
  *(u16x4*)(dst + 4) = *(u16x4*)(o + 4);
}

__global__ __launch_bounds__(512)
void proj_gemm(const float* __restrict__ X, const unsigned short* __restrict__ Wswz,
               const float* __restrict__ bias, float* __restrict__ Out) {
  __shared__ unsigned short Xl[32 * 256];
  const int tid = threadIdx.x;
  const int lane = tid & 63, wid = tid >> 6;
  const int wr = wid >> 1, wc = wid & 1;
  const int b = blockIdx.x >> 7;
  const int m0 = (blockIdx.x & 127) * 32;
  const float* Xb = X + (size_t)b * DM_ * M_ + m0;
  const int c4 = 4 * (tid & 7);
  const int ch0 = 4 * (tid >> 3);
  float4 f[4];
#pragma unroll
  for (int i = 0; i < 4; ++i) f[i] = *(const float4*)(Xb + (size_t)(ch0 + i) * M_ + c4);
#pragma unroll
  for (int j = 0; j < 4; ++j) {
    u16x4 u = { f2bf(((const float*)&f[0])[j]), f2bf(((const float*)&f[1])[j]),
                f2bf(((const float*)&f[2])[j]), f2bf(((const float*)&f[3])[j]) };
    *(u16x4*)((char*)Xl + swz512(c4 + j, 2 * ch0)) = u;
  }
  __syncthreads();
  f32x4 acc[4] = {};
  const int bcol = wc * 16 + (lane & 15);
  const int rdk = 16 * (lane >> 4);
  short8 a_cur[4], a_nxt[4];
#pragma unroll
  for (int fi = 0; fi < 4; ++fi)
    a_cur[fi] = *(const short8*)(Wswz + (size_t)(((wr * 4 + fi) * 64 + lane) * 8));
#pragma unroll
  for (int kgs = 0; kgs < 8; ++kgs) {
    if (kgs < 7) {
#pragma unroll
      for (int fi = 0; fi < 4; ++fi)
        a_nxt[fi] = *(const short8*)(Wswz + (size_t)(((((kgs + 1) * 16) + wr * 4 + fi) * 64 + lane) * 8));
    }
    short8 bb = *(const short8*)((const char*)Xl + swz512(bcol, 64 * kgs + rdk));
#pragma unroll
    for (int fi = 0; fi < 4; ++fi)
      acc[fi] = __builtin_amdgcn_mfma_f32_16x16x32_bf16(a_cur[fi], bb, acc[fi], 0, 0, 0);
#pragma unroll
    for (int fi = 0; fi < 4; ++fi) a_cur[fi] = a_nxt[fi];
  }
#pragma unroll
  for (int fi = 0; fi < 4; ++fi) {
#pragma unroll
    for (int r = 0; r < 4; ++r) {
      const int co = wr * 64 + fi * 16 + (lane >> 4) * 4 + r;
      Out[(size_t)(b * DM_ + co) * M_ + m0 + bcol] = acc[fi][r] + bias[co];
    }
  }
}

__global__ __launch_bounds__(1024, 4)
void fused_attn(const float* __restrict__ key, const float* __restrict__ value,
                const float* __restrict__ qws,
                const unsigned short* __restrict__ Wk_swz, const unsigned short* __restrict__ Wv_swz,
                const float* __restrict__ bk, const float* __restrict__ bv,
                float* __restrict__ xws, float* __restrict__ psum) {
  __shared__ unsigned short Xlds[2][128 * 64];
  __shared__ float q_lds[8][DM_];
  __shared__ float bk_lds[DM_];
  __shared__ float scx[4][4][8][16];
  __shared__ float prob_lds[4][8][16];
  float (*x_lds)[DM_] = (float (*)[DM_])scx;
  const int tid = threadIdx.x;
  const int lane = tid & 63, wid = tid >> 6;
  const int wr = wid >> 2, wc = wid & 3;
  const int b = blockIdx.x >> 9;
  const int m0 = (blockIdx.x & 511) * 8;
  const float* keyb = key + (size_t)b * DM_ * MK_;
  const float* valb = value + (size_t)b * DM_ * MK_;
  {
    const int c = tid >> 2, mh = (tid & 3) * 2;
    const float2 qv = *(const float2*)(qws + (size_t)(b * DM_ + c) * M_ + m0 + mh);
    q_lds[mh][c] = qv.x; q_lds[mh + 1][c] = qv.y;
    if (tid < DM_) bk_lds[tid] = bk[tid];
  }
  f32x4 acc[4][2] = {};
  const int c4 = 4 * (tid & 31);
  const int ch = 2 * (tid >> 5);
  const size_t colbase = (size_t)m0 * KN_ + c4;
  const int wkbyte = 4 * (tid >> 5);
  float4 fa, fb2;
  fa  = *(const float4*)(keyb + (size_t)ch * MK_ + colbase);
  fb2 = *(const float4*)(keyb + (size_t)(ch + 1) * MK_ + colbase);
  for (int p = 0; p < 8; ++p) {
    unsigned short* Xb = Xlds[p & 1];
#pragma unroll
    for (int j = 0; j < 4; ++j) {
      uint32_t u = (uint32_t)f2bf(((const float*)&fa)[j]) |
                   ((uint32_t)f2bf(((const float*)&fb2)[j]) << 16);
      *(uint32_t*)((char*)Xb + swz128(c4 + j, wkbyte)) = u;
    }
    __syncthreads();
    const unsigned short* Wsw = (p < 4) ? Wk_swz : Wv_swz;
    short8 afr[2][4];
#pragma unroll
    for (int ks = 0; ks < 2; ++ks)
#pragma unroll
      for (int fi = 0; fi < 4; ++fi)
        afr[ks][fi] = *(const short8*)(Wsw +
            (size_t)(((((p & 3) * 2 + ks) * 16 + wr * 4 + fi) * 64 + lane) * 8));
    if (p < 7) {
      const float* src = (p < 3) ? keyb : valb;
      const size_t base = (size_t)(((p + 1) & 3) * 64 + ch) * MK_ + colbase;
      fa  = *(const float4*)(src + base);
      fb2 = *(const float4*)(src + base + MK_);
    }
#pragma unroll
    for (int ks = 0; ks < 2; ++ks) {
      short8 bfr[2];
#pragma unroll
      for (int fj = 0; fj < 2; ++fj)
        bfr[fj] = *(const short8*)((const char*)Xb +
            swz128(wc * 32 + fj * 16 + (lane & 15), 64 * ks + 16 * (lane >> 4)));
#pragma unroll
      for (int fi = 0; fi < 4; ++fi)
#pragma unroll
        for (int fj = 0; fj < 2; ++fj)
          acc[fi][fj] = __builtin_amdgcn_mfma_f32_16x16x32_bf16(afr[ks][fi], bfr[fj], acc[fi][fj], 0, 0, 0);
    }
    if (p == 3) {
      float part[4][2];
#pragma unroll
      for (int h = 0; h < 4; ++h)
#pragma unroll
        for (int fj = 0; fj < 2; ++fj) part[h][fj] = 0.f;
#pragma unroll
      for (int fj = 0; fj < 2; ++fj) {
        const int mp = wc * 2 + fj;
#pragma unroll
        for (int fi = 0; fi < 4; ++fi) {
          const int d = wr * 16 + fi * 4 + (lane >> 4);
#pragma unroll
          for (int h = 0; h < 4; ++h) {
            const int c = 4 * d + h;
            part[h][fj] += q_lds[mp][c] * (acc[fi][fj][h] + bk_lds[c]);
          }
        }
      }
#pragma unroll
      for (int h = 0; h < 4; ++h)
#pragma unroll
        for (int fj = 0; fj < 2; ++fj) {
          float v = part[h][fj];
          v += __shfl_xor(v, 16);
          v += __shfl_xor(v, 32);
          if (lane < 16) scx[wr][h][wc * 2 + fj][lane] = v;
        }
      __syncthreads();
      if (tid < 512) {
        const int h = tid >> 7, mp = (tid >> 4) & 7, kk = tid & 15;
        float s = (scx[0][h][mp][kk] + scx[1][h][mp][kk] +
                   scx[2][h][mp][kk] + scx[3][h][mp][kk]) * 0.125f;
        float mx = s;
#pragma unroll
        for (int d2 = 1; d2 < 16; d2 <<= 1) mx = fmaxf(mx, __shfl_xor(mx, d2));
        const float e = __expf(s - mx);
        float sm = e;
#pragma unroll
        for (int d2 = 1; d2 < 16; d2 <<= 1) sm += __shfl_xor(sm, d2);
        prob_lds[h][mp][kk] = e / sm;
      }
      __syncthreads();
      if (tid < 128) {
        const int mp = tid >> 4, kk = tid & 15;
        psum[(size_t)(b * M_ + m0 + mp) * KN_ + kk] =
            prob_lds[0][mp][kk] + prob_lds[1][mp][kk] + prob_lds[2][mp][kk] + prob_lds[3][mp][kk];
      }
      const f32x4 z = {0.f, 0.f, 0.f, 0.f};
#pragma unroll
      for (int fi = 0; fi < 4; ++fi)
#pragma unroll
        for (int fj = 0; fj < 2; ++fj) acc[fi][fj] = z;
    }
  }
#pragma unroll
  for (int fi = 0; fi < 4; ++fi)
#pragma unroll
    for (int fj = 0; fj < 2; ++fj) {
      const int mp = wc * 2 + fj;
#pragma unroll
      for (int r = 0; r < 4; ++r) {
        float v = prob_lds[r][mp][lane & 15] * acc[fi][fj][r];
        v += __shfl_xor(v, 1);
        v += __shfl_xor(v, 2);
        v += __shfl_xor(v, 4);
        v += __shfl_xor(v, 8);
        if ((lane & 15) == 0) x_lds[mp][wr * 64 + fi * 16 + (lane >> 4) * 4 + r] = v;
      }
    }
  __syncthreads();
  {
    const int c = tid >> 2, mh = (tid & 3) * 2;
    const float bvv = bv[c];
    float2 o;
    o.x = x_lds[mh][c] + bvv;
    o.y = x_lds[mh + 1][c] + bvv;
    *(float2*)(xws + (size_t)(b * DM_ + c) * M_ + m0 + mh) = o;
  }
}

extern "C" void kernel_launch(void* const* d_in, const int* in_sizes, int n_in,
                              void* d_out, int out_size, void* d_ws, size_t ws_size,
                              hipStream_t stream) {
  const float* query = (const float*)d_in[0];
  const float* key   = (const float*)d_in[1];
  const float* value = (const float*)d_in[2];
  const float* Wq = (const float*)d_in[3];
  const float* bq = (const float*)d_in[4];
  const float* Wk = (const float*)d_in[5];
  const float* bk = (const float*)d_in[6];
  const float* Wv = (const float*)d_in[7];
  const float* bv = (const float*)d_in[8];
  const float* Wm = (const float*)d_in[9];
  const float* bm = (const float*)d_in[10];
  float* out  = (float*)d_out;
  float* psum = out + (size_t)B_ * DM_ * M_;

  // ---- new-path workspace layout ----
  const size_t W2T_off  = 0;                        // 512 KB bf16
  const size_t Wmv_off  = 524288;                   // 512 KB bf16
  const size_t qb2_off  = 1048576;                  // 4 KB f32
  const size_t btot_off = 1052672;                  // 1 KB f32
  const size_t qW_off   = 1053696;                  // 16.78 MB bf16
  const size_t pv_off   = qW_off + (size_t)B_ * 1024 * M_ * 2;
  const size_t need     = pv_off + (size_t)B_ * M_ * 1024 * 2;

  if (ws_size >= need) {
    unsigned short* W2T   = (unsigned short*)d_ws;
    unsigned short* Wmv   = (unsigned short*)((char*)d_ws + Wmv_off);
    float* qb2            = (float*)((char*)d_ws + qb2_off);
    float* btot           = (float*)((char*)d_ws + btot_off);
    unsigned short* qWbuf = (unsigned short*)((char*)d_ws + qW_off);
    unsigned short* pvbuf = (unsigned short*)((char*)d_ws + pv_off);
    prep2<<<dim3(1027), dim3(512), 0, stream>>>(Wq, bq, Wk, Wv, bv, Wm, bm, W2T, Wmv, qb2, btot);
    qw_gemm<<<dim3(B_ * 4 * 128), dim3(512), 0, stream>>>(query, W2T, qb2, qWbuf);
    attn_stream<<<dim3(B_ * (M_ / 8)), dim3(512), 0, stream>>>(key, value, qWbuf, pvbuf, psum);
    out_gemm<<<dim3(B_ * 128), dim3(512), 0, stream>>>(pvbuf, Wmv, btot, out);
  } else {
    // ---- old path ----
    unsigned short* Wswz = (unsigned short*)d_ws;
    const size_t wbytes = (size_t)4 * 65536 * sizeof(unsigned short);
    const size_t qbytes = (size_t)B_ * DM_ * M_ * sizeof(float);
    float* qws;
    if (ws_size >= wbytes + qbytes) qws = (float*)((char*)d_ws + wbytes);
    else qws = out;
    float* xws = qws;
    prep_weights<<<dim3(128), dim3(256), 0, stream>>>(Wq, Wk, Wv, Wm, Wswz);
    proj_gemm<<<dim3(B_ * (M_ / 32)), dim3(512), 0, stream>>>(query, Wswz + 0 * 65536, bq, qws);
    fused_attn<<<dim3(B_ * (M_ / 8)), dim3(1024), 0, stream>>>(key, value, qws,
                                                               Wswz + 1 * 65536, Wswz + 2 * 65536,
                                                               bk, bv, xws, psum);
    proj_gemm<<<dim3(B_ * (M_ / 32)), dim3(512), 0, stream>>>(xws, Wswz + 3 * 65536, bm, out);
  }
}